// Round 5
// baseline (403.882 us; speedup 1.0000x reference)
//
#include <hip/hip_runtime.h>
#include <hip/hip_bf16.h>

#define B_ 4
#define S_ 2048
#define E_ 768
#define H_ 12
#define D_ 64
#define M_ (B_*S_)      // 8192
#define NQKV 2304
#define KDIM 768

typedef __bf16 bf16x8 __attribute__((ext_vector_type(8)));
typedef float f32x4 __attribute__((ext_vector_type(4)));
typedef unsigned int uintx4 __attribute__((ext_vector_type(4)));

typedef __attribute__((address_space(1))) void gvoid;
typedef __attribute__((address_space(3))) void lvoid;

__device__ __forceinline__ void gl_lds16(const void* g, void* l) {
  __builtin_amdgcn_global_load_lds((gvoid*)g, (lvoid*)l, 16, 0, 0);
}

__device__ __forceinline__ f32x4 mfma16(bf16x8 a, bf16x8 b, f32x4 c) {
  return __builtin_amdgcn_mfma_f32_16x16x32_bf16(a, b, c, 0, 0, 0);
}

// pack two f32 -> packed bf16 pair (RNE via (__bf16) cast)
__device__ __forceinline__ unsigned int pk2(float a, float b) {
  unsigned short ua = __builtin_bit_cast(unsigned short, (__bf16)a);
  unsigned short ub = __builtin_bit_cast(unsigned short, (__bf16)b);
  return (unsigned int)ua | ((unsigned int)ub << 16);
}

// Load element idx from a buffer that is either bf16 (is_bf=1) or fp32 (is_bf=0).
__device__ __forceinline__ __bf16 ldmix(const void* p, size_t idx, int is_bf) {
  if (is_bf) return ((const __bf16*)p)[idx];
  return (__bf16)(((const float*)p)[idx]);
}
__device__ __forceinline__ float ldmixf(const void* p, size_t idx, int is_bf) {
  if (is_bf) return (float)((const __bf16*)p)[idx];
  return ((const float*)p)[idx];
}

// ---------------- dtype detector (even u16 of fp32 = random mantissa bits) ----------------
__global__ void detect_kernel(const unsigned short* __restrict__ xr, int* __restrict__ flag) {
  __shared__ int cnt;
  if (threadIdx.x == 0) cnt = 0;
  __syncthreads();
  unsigned short h = xr[2 * threadIdx.x];
  int e = (h >> 7) & 0xFF;
  if (e >= 100 && e <= 140) atomicAdd(&cnt, 1);
  __syncthreads();
  if (threadIdx.x == 0) *flag = (cnt > 148) ? 1 : 0;   // 1 = inputs are bf16
}

// ---------------- x -> bf16 ----------------
__global__ __launch_bounds__(256) void convx_kernel(const void* __restrict__ x,
                                                    const int* __restrict__ flag,
                                                    __bf16* __restrict__ Xb) {
  const int is_bf = *flag;
  int idx = blockIdx.x * 256 + threadIdx.x;   // < 6291456
  Xb[idx] = ldmix(x, idx, is_bf);
}

// ---------------- weight pack + maskAdd precompute ----------------
__global__ __launch_bounds__(256) void pack_kernel(
    const void* __restrict__ Wq, const void* __restrict__ bq,
    const void* __restrict__ Wk, const void* __restrict__ bk,
    const void* __restrict__ Wv, const void* __restrict__ bv,
    const void* __restrict__ Wo, const void* __restrict__ bo,
    const int* __restrict__ mask,
    const int* __restrict__ flag,
    __bf16* __restrict__ WbT, __bf16* __restrict__ WoT,
    float* __restrict__ biasP, float* __restrict__ biasO,
    float* __restrict__ maskAdd)
{
  const int is_bf = *flag;
  int idx = blockIdx.x * 256 + threadIdx.x;
  const int NW = NQKV * KDIM;   // 1769472
  if (idx < NW) {
    int n = idx / KDIM;
    int e = idx - n * KDIM;
    int sel = n / 768;
    int hd  = n - sel * 768;
    int h = hd >> 6, d = hd & 63;
    const void* W = (sel == 0) ? Wq : (sel == 1) ? Wk : Wv;
    WbT[idx] = ldmix(W, (size_t)(h * 768 + e) * 64 + d, is_bf);
  } else {
    int idx2 = idx - NW;        // < 589824
    int n = idx2 / 768;
    int k = idx2 - n * 768;
    WoT[idx2] = ldmix(Wo, (size_t)k * 768 + n, is_bf);
  }
  if (idx < NQKV) {
    int sel = idx / 768;
    int hd = idx - sel * 768;
    const void* bsel = (sel == 0) ? bq : (sel == 1) ? bk : bv;
    biasP[idx] = ldmixf(bsel, hd, is_bf);
  }
  if (idx >= NW && idx < NW + 768) {
    biasO[idx - NW] = ldmixf(bo, idx - NW, is_bf);
  }
  if (idx < B_ * S_) {
    maskAdd[idx] = (mask[idx] == 0) ? -1.0e9f : 0.0f;
  }
}

// ---------------- GEMM: C[M][N] = A[M][K] * Bt[N][K]^T + bias[N]  (m97 structure) ----------------
__global__ __launch_bounds__(256) void gemm_bt_bias(
    const __bf16* __restrict__ A,
    const __bf16* __restrict__ Bt,
    const float* __restrict__ bias,
    void* __restrict__ C,
    int N, int K,
    const int* __restrict__ flag, int force_bf16)
{
  __shared__ __align__(16) __bf16 As[128 * 32];
  __shared__ __align__(16) __bf16 Bs[128 * 32];
  const int obf = force_bf16 | *flag;
  const int t = threadIdx.x;
  const int wave = t >> 6, lane = t & 63;
  const int l15 = lane & 15, lq = lane >> 4;
  const int m0 = blockIdx.x * 128;
  const int n0 = blockIdx.y * 128;
  const int wr = (wave >> 1) * 64;
  const int wc = (wave & 1) * 64;

  const f32x4 z4 = {0.f, 0.f, 0.f, 0.f};
  f32x4 acc[4][4];
  for (int i = 0; i < 4; ++i)
    for (int j = 0; j < 4; ++j) acc[i][j] = z4;

  for (int k0 = 0; k0 < K; k0 += 32) {
    __syncthreads();
    for (int p = 0; p < 2; ++p) {
      int chunk = p * 256 + t;
      int row = chunk >> 2, c8 = (chunk & 3) << 3;
      gl_lds16(A  + (size_t)(m0 + row) * K + k0 + c8, As + (size_t)(p * 256 + wave * 64) * 8);
      gl_lds16(Bt + (size_t)(n0 + row) * K + k0 + c8, Bs + (size_t)(p * 256 + wave * 64) * 8);
    }
    __syncthreads();
    bf16x8 af[4], bfr[4];
    for (int i = 0; i < 4; ++i) af[i]  = *(const bf16x8*)(As + (wr + i * 16 + l15) * 32 + lq * 8);
    for (int j = 0; j < 4; ++j) bfr[j] = *(const bf16x8*)(Bs + (wc + j * 16 + l15) * 32 + lq * 8);
    for (int i = 0; i < 4; ++i)
      for (int j = 0; j < 4; ++j)
        acc[i][j] = mfma16(af[i], bfr[j], acc[i][j]);
  }

  for (int j = 0; j < 4; ++j) {
    int n = n0 + wc + j * 16 + l15;
    float bv = bias[n];
    for (int i = 0; i < 4; ++i) {
      int mbase = m0 + wr + i * 16 + lq * 4;
      for (int r = 0; r < 4; ++r) {
        size_t off = (size_t)(mbase + r) * N + n;
        float val = acc[i][j][r] + bv;
        if (obf) ((__bf16*)C)[off] = (__bf16)val;
        else     ((float*)C)[off]  = val;
      }
    }
  }
}

// ---------------- V transpose: VT[bh][d][s] = QKV.V[b][s][h][d] ----------------
__global__ __launch_bounds__(256) void vtrans_kernel(
    const __bf16* __restrict__ QKV, __bf16* __restrict__ VTg)
{
  __shared__ __bf16 tile[64][72];
  const int t = threadIdx.x;
  const int bh = blockIdx.y;
  const int b = bh / H_, h = bh - b * H_;
  const int s0 = blockIdx.x * 64;
  const __bf16* Vb = QKV + (size_t)b * S_ * NQKV + 1536 + h * 64;
  for (int rr = 0; rr < 2; ++rr) {
    int srow = rr * 32 + (t >> 3);
    int dcol = (t & 7) * 8;
    *(bf16x8*)&tile[srow][dcol] = *(const bf16x8*)(Vb + (size_t)(s0 + srow) * NQKV + dcol);
  }
  __syncthreads();
  for (int rr = 0; rr < 2; ++rr) {
    int drow = rr * 32 + (t >> 3);
    int sc = (t & 7) * 8;
    bf16x8 v;
    for (int j = 0; j < 8; ++j) v[j] = tile[sc + j][drow];
    *(bf16x8*)(VTg + ((size_t)bh * 64 + drow) * S_ + s0 + sc) = v;
  }
}

// ---------------- attention: direct-global fragments, no LDS staging, no K-loop barriers ----
// Per block: one (b,h), 128 q rows (32/wave). 64-key tiles; K/V frags loaded straight from
// L2/L3-resident global (K/V per bh = 512 KB; QKV total 37.7 MB -> L3-cached).
__global__ __launch_bounds__(256, 3) void attn_kernel(
    const __bf16* __restrict__ QKV,    // [M][2304] (b,s,{q,k,v},h,d)
    const __bf16* __restrict__ VTg,    // [48][64][2048]
    const float* __restrict__ maskAdd, // [4][2048]: 0 or -1e9
    __bf16* __restrict__ Out)          // [M][768] (b,s,h,d)
{
  const int t = threadIdx.x;
  const int w = t >> 6, lane = t & 63;
  const int l15 = lane & 15, qd = lane >> 4;
  const int bh = blockIdx.x;              // bh on x: same-bh blocks land on one XCD
  const int b = bh / H_, h = bh - b * H_;
  const int q0 = blockIdx.y * 128;

  const __bf16* Qb = QKV + (size_t)b * S_ * NQKV + h * 64;
  const __bf16* Kb = Qb + 768;
  const __bf16* Vg = VTg + (size_t)bh * 64 * S_;
  const float* mb = maskAdd + b * S_;

  // Q fragments (B-operand: n=q at l15, k=d at qd*8+j): 2 q-subtiles x 2 d-halves
  bf16x8 qf[2][2];
#pragma unroll
  for (int sub = 0; sub < 2; ++sub) {
    int qrow = q0 + w * 32 + sub * 16 + l15;
    qf[sub][0] = *(const bf16x8*)(Qb + (size_t)qrow * NQKV + qd * 8);
    qf[sub][1] = *(const bf16x8*)(Qb + (size_t)qrow * NQKV + 32 + qd * 8);
  }

  const f32x4 z4 = {0.f, 0.f, 0.f, 0.f};
  f32x4 o[2][4];
#pragma unroll
  for (int sub = 0; sub < 2; ++sub)
#pragma unroll
    for (int dt = 0; dt < 4; ++dt) o[sub][dt] = z4;
  float lac[2] = {0.f, 0.f};

  const float SC = 0.18033688011112042f;  // 0.125 * log2(e)
  const int src0 = l15 + 32 * (qd & 1);
  const int src1 = src0 + 16;
  const bool lo = (qd < 2);

  for (int k0 = 0; k0 < S_; k0 += 64) {
    // K fragments (A-operand: m=key at l15, k=d): 4 key-tiles x 2 d-halves — direct global
    bf16x8 kf[4][2];
#pragma unroll
    for (int kt = 0; kt < 4; ++kt) {
      const __bf16* kr = Kb + (size_t)(k0 + kt * 16 + l15) * NQKV + qd * 8;
      kf[kt][0] = *(const bf16x8*)(kr);
      kf[kt][1] = *(const bf16x8*)(kr + 32);
    }
    // V fragments (B-operand: n=d at l15, k=key): 2 key-halves x 4 d-tiles — direct global
    bf16x8 vf[2][4];
#pragma unroll
    for (int dt = 0; dt < 4; ++dt) {
      const __bf16* vr = Vg + (size_t)(dt * 16 + l15) * S_ + k0 + qd * 8;
      vf[0][dt] = *(const bf16x8*)(vr);
      vf[1][dt] = *(const bf16x8*)(vr + 32);
    }
    // mask adds for this tile (keys kt*16 + qd*4 + r)
    f32x4 ma[4];
#pragma unroll
    for (int kt = 0; kt < 4; ++kt) ma[kt] = *(const f32x4*)(mb + k0 + kt * 16 + qd * 4);

#pragma unroll
    for (int sub = 0; sub < 2; ++sub) {
      // S^T = K * Q^T : lane holds q=l15, keys kt*16+4qd+r
      f32x4 s[4];
#pragma unroll
      for (int kt = 0; kt < 4; ++kt) {
        s[kt] = mfma16(kf[kt][0], qf[sub][0], z4);
        s[kt] = mfma16(kf[kt][1], qf[sub][1], s[kt]);
      }
      // p = exp2(s*SC + madd); accumulate l; pack pairs
      unsigned int pk[4][2];
#pragma unroll
      for (int kt = 0; kt < 4; ++kt) {
        float p0 = __builtin_amdgcn_exp2f(__builtin_fmaf(s[kt][0], SC, ma[kt][0]));
        float p1 = __builtin_amdgcn_exp2f(__builtin_fmaf(s[kt][1], SC, ma[kt][1]));
        float p2 = __builtin_amdgcn_exp2f(__builtin_fmaf(s[kt][2], SC, ma[kt][2]));
        float p3 = __builtin_amdgcn_exp2f(__builtin_fmaf(s[kt][3], SC, ma[kt][3]));
        lac[sub] += (p0 + p1) + (p2 + p3);
        pk[kt][0] = pk2(p0, p1);
        pk[kt][1] = pk2(p2, p3);
      }
      // transpose to A-operand frags via bpermute: frag0 = keys 0..31, frag1 = 32..63
      unsigned int a0, a1, a2, a3, b0, b1, b2, b3;
      a0 = (unsigned int)__shfl((int)pk[0][0], src0); b0 = (unsigned int)__shfl((int)pk[1][0], src0);
      a1 = (unsigned int)__shfl((int)pk[0][1], src0); b1 = (unsigned int)__shfl((int)pk[1][1], src0);
      a2 = (unsigned int)__shfl((int)pk[0][0], src1); b2 = (unsigned int)__shfl((int)pk[1][0], src1);
      a3 = (unsigned int)__shfl((int)pk[0][1], src1); b3 = (unsigned int)__shfl((int)pk[1][1], src1);
      uintx4 u0 = { lo ? a0 : b0, lo ? a1 : b1, lo ? a2 : b2, lo ? a3 : b3 };
      a0 = (unsigned int)__shfl((int)pk[2][0], src0); b0 = (unsigned int)__shfl((int)pk[3][0], src0);
      a1 = (unsigned int)__shfl((int)pk[2][1], src0); b1 = (unsigned int)__shfl((int)pk[3][1], src0);
      a2 = (unsigned int)__shfl((int)pk[2][0], src1); b2 = (unsigned int)__shfl((int)pk[3][0], src1);
      a3 = (unsigned int)__shfl((int)pk[2][1], src1); b3 = (unsigned int)__shfl((int)pk[3][1], src1);
      uintx4 u1 = { lo ? a0 : b0, lo ? a1 : b1, lo ? a2 : b2, lo ? a3 : b3 };
      bf16x8 pf0 = __builtin_bit_cast(bf16x8, u0);
      bf16x8 pf1 = __builtin_bit_cast(bf16x8, u1);
      // O += P V
#pragma unroll
      for (int dt = 0; dt < 4; ++dt) {
        o[sub][dt] = mfma16(pf0, vf[0][dt], o[sub][dt]);
        o[sub][dt] = mfma16(pf1, vf[1][dt], o[sub][dt]);
      }
    }
  }

  // finalize: reduce l over quads, broadcast to output layout, divide, store
#pragma unroll
  for (int sub = 0; sub < 2; ++sub) {
    float l = lac[sub];
    l += __shfl_xor(l, 16);
    l += __shfl_xor(l, 32);          // lane(l15,qd) now has l(q=l15)
    float lt[4];
#pragma unroll
    for (int r = 0; r < 4; ++r) lt[r] = __shfl(l, qd * 4 + r);
#pragma unroll
    for (int dt = 0; dt < 4; ++dt)
#pragma unroll
      for (int r = 0; r < 4; ++r) {
        int qrow = q0 + w * 32 + sub * 16 + qd * 4 + r;
        Out[(size_t)(b * S_ + qrow) * E_ + h * 64 + dt * 16 + l15] =
            (__bf16)(o[sub][dt][r] / lt[r]);
      }
  }
}

extern "C" void kernel_launch(void* const* d_in, const int* in_sizes, int n_in,
                              void* d_out, int out_size, void* d_ws, size_t ws_size,
                              hipStream_t stream) {
  const void* x  = d_in[0];
  const int* mask = (const int*)d_in[1];
  const void* Wq = d_in[2];
  const void* bq = d_in[3];
  const void* Wk = d_in[4];
  const void* bk = d_in[5];
  const void* Wv = d_in[6];
  const void* bv = d_in[7];
  const void* Wo = d_in[8];
  const void* bo = d_in[9];

  char* ws = (char*)d_ws;
  int*    flag  = (int*)(ws + 0);
  __bf16* Xb    = (__bf16*)(ws + 256);        // 12582912 B -> ends 12583168
  __bf16* VTg   = Xb;                         // aliases Xb (dead after gemm1)
  __bf16* WbT   = (__bf16*)(ws + 12583168);   // 3538944  -> 16122112
  __bf16* WoT   = (__bf16*)(ws + 16122112);   // 1179648  -> 17301760
  float*  biasP = (float*)(ws + 17301760);    // 9216     -> 17310976
  float*  biasO = (float*)(ws + 17310976);    // 3072     -> 17314048
  __bf16* QKV   = (__bf16*)(ws + 17314048);   // 37748736 -> 55062784
  __bf16* attnO = (__bf16*)(ws + 55062784);   // 12582912 -> 67645696
  float*  maskA = (float*)(ws + 67645696);    // 32768    -> 67678464

  detect_kernel<<<dim3(1), dim3(256), 0, stream>>>((const unsigned short*)x, flag);
  convx_kernel<<<dim3(24576), dim3(256), 0, stream>>>(x, flag, Xb);
  pack_kernel<<<dim3(9216), dim3(256), 0, stream>>>(Wq, bq, Wk, bk, Wv, bv, Wo, bo, mask, flag,
                                                    WbT, WoT, biasP, biasO, maskA);
  gemm_bt_bias<<<dim3(64, 18), dim3(256), 0, stream>>>(Xb, WbT, biasP, QKV, NQKV, KDIM, flag, 1);
  vtrans_kernel<<<dim3(32, 48), dim3(256), 0, stream>>>(QKV, VTg);
  attn_kernel<<<dim3(48, 16), dim3(256), 0, stream>>>(QKV, VTg, maskA, attnO);
  gemm_bt_bias<<<dim3(64, 6), dim3(256), 0, stream>>>(attnO, WoT, biasO, d_out, E_, KDIM, flag, 0);
}

// Round 6
// 292.573 us; speedup vs baseline: 1.3804x; 1.3804x over previous
//
#include <hip/hip_runtime.h>
#include <hip/hip_bf16.h>

#define B_ 4
#define S_ 2048
#define E_ 768
#define H_ 12
#define D_ 64
#define M_ (B_*S_)      // 8192
#define NQKV 2304
#define KDIM 768

typedef __bf16 bf16x8 __attribute__((ext_vector_type(8)));
typedef float f32x4 __attribute__((ext_vector_type(4)));
typedef short shortx4 __attribute__((ext_vector_type(4)));
typedef unsigned int uintx2 __attribute__((ext_vector_type(2)));
typedef unsigned int uintx4 __attribute__((ext_vector_type(4)));

typedef __attribute__((address_space(1))) void gvoid;
typedef __attribute__((address_space(3))) void lvoid;

__device__ __forceinline__ void gl_lds16(const void* g, void* l) {
  __builtin_amdgcn_global_load_lds((gvoid*)g, (lvoid*)l, 16, 0, 0);
}

__device__ __forceinline__ f32x4 mfma16(bf16x8 a, bf16x8 b, f32x4 c) {
  return __builtin_amdgcn_mfma_f32_16x16x32_bf16(a, b, c, 0, 0, 0);
}

// PV MFMA: 16x16 tile, K=16. A/B: 4 bf16/lane, k = quad*4 + elem.
__device__ __forceinline__ f32x4 mfma_pv(shortx4 a, shortx4 b, f32x4 c) {
#if __has_builtin(__builtin_amdgcn_mfma_f32_16x16x16bf16_1k)
  return __builtin_amdgcn_mfma_f32_16x16x16bf16_1k(a, b, c, 0, 0, 0);
#else
  // zero-pad to K=32: slots j=0..3 of each quad carry the 4 keys on both A and B;
  // slots 4..7 are zero on both sides -> identical partial sum.
  uintx2 au = __builtin_bit_cast(uintx2, a);
  uintx2 bu = __builtin_bit_cast(uintx2, b);
  uintx4 aw = {au.x, au.y, 0u, 0u};
  uintx4 bw = {bu.x, bu.y, 0u, 0u};
  return mfma16(__builtin_bit_cast(bf16x8, aw), __builtin_bit_cast(bf16x8, bw), c);
#endif
}

// Load element idx from a buffer that is either bf16 (is_bf=1) or fp32 (is_bf=0).
__device__ __forceinline__ __bf16 ldmix(const void* p, size_t idx, int is_bf) {
  if (is_bf) return ((const __bf16*)p)[idx];
  return (__bf16)(((const float*)p)[idx]);
}
__device__ __forceinline__ float ldmixf(const void* p, size_t idx, int is_bf) {
  if (is_bf) return (float)((const __bf16*)p)[idx];
  return ((const float*)p)[idx];
}

// ---------------- dtype detector (even u16 of fp32 = random mantissa bits) ----------------
__global__ void detect_kernel(const unsigned short* __restrict__ xr, int* __restrict__ flag) {
  __shared__ int cnt;
  if (threadIdx.x == 0) cnt = 0;
  __syncthreads();
  unsigned short h = xr[2 * threadIdx.x];
  int e = (h >> 7) & 0xFF;
  if (e >= 100 && e <= 140) atomicAdd(&cnt, 1);
  __syncthreads();
  if (threadIdx.x == 0) *flag = (cnt > 148) ? 1 : 0;   // 1 = inputs are bf16
}

// ---------------- x -> bf16 ----------------
__global__ __launch_bounds__(256) void convx_kernel(const void* __restrict__ x,
                                                    const int* __restrict__ flag,
                                                    __bf16* __restrict__ Xb) {
  const int is_bf = *flag;
  int idx = blockIdx.x * 256 + threadIdx.x;   // < 6291456
  Xb[idx] = ldmix(x, idx, is_bf);
}

// ---------------- weight pack + maskAdd precompute ----------------
__global__ __launch_bounds__(256) void pack_kernel(
    const void* __restrict__ Wq, const void* __restrict__ bq,
    const void* __restrict__ Wk, const void* __restrict__ bk,
    const void* __restrict__ Wv, const void* __restrict__ bv,
    const void* __restrict__ Wo, const void* __restrict__ bo,
    const int* __restrict__ mask,
    const int* __restrict__ flag,
    __bf16* __restrict__ WbT, __bf16* __restrict__ WoT,
    float* __restrict__ biasP, float* __restrict__ biasO,
    float* __restrict__ maskAdd)
{
  const int is_bf = *flag;
  int idx = blockIdx.x * 256 + threadIdx.x;
  const int NW = NQKV * KDIM;   // 1769472
  if (idx < NW) {
    int n = idx / KDIM;
    int e = idx - n * KDIM;
    int sel = n / 768;
    int hd  = n - sel * 768;
    int h = hd >> 6, d = hd & 63;
    const void* W = (sel == 0) ? Wq : (sel == 1) ? Wk : Wv;
    WbT[idx] = ldmix(W, (size_t)(h * 768 + e) * 64 + d, is_bf);
  } else {
    int idx2 = idx - NW;        // < 589824
    int n = idx2 / 768;
    int k = idx2 - n * 768;
    WoT[idx2] = ldmix(Wo, (size_t)k * 768 + n, is_bf);
  }
  if (idx < NQKV) {
    int sel = idx / 768;
    int hd = idx - sel * 768;
    const void* bsel = (sel == 0) ? bq : (sel == 1) ? bk : bv;
    biasP[idx] = ldmixf(bsel, hd, is_bf);
  }
  if (idx >= NW && idx < NW + 768) {
    biasO[idx - NW] = ldmixf(bo, idx - NW, is_bf);
  }
  if (idx < B_ * S_) {
    maskAdd[idx] = (mask[idx] == 0) ? -1.0e9f : 0.0f;
  }
}

// ---------------- GEMM: C[M][N] = A[M][K] * Bt[N][K]^T + bias[N]  (m97 structure) ----------------
__global__ __launch_bounds__(256) void gemm_bt_bias(
    const __bf16* __restrict__ A,
    const __bf16* __restrict__ Bt,
    const float* __restrict__ bias,
    void* __restrict__ C,
    int N, int K,
    const int* __restrict__ flag, int force_bf16)
{
  __shared__ __align__(16) __bf16 As[128 * 32];
  __shared__ __align__(16) __bf16 Bs[128 * 32];
  const int obf = force_bf16 | *flag;
  const int t = threadIdx.x;
  const int wave = t >> 6, lane = t & 63;
  const int l15 = lane & 15, lq = lane >> 4;
  const int m0 = blockIdx.x * 128;
  const int n0 = blockIdx.y * 128;
  const int wr = (wave >> 1) * 64;
  const int wc = (wave & 1) * 64;

  const f32x4 z4 = {0.f, 0.f, 0.f, 0.f};
  f32x4 acc[4][4];
  for (int i = 0; i < 4; ++i)
    for (int j = 0; j < 4; ++j) acc[i][j] = z4;

  for (int k0 = 0; k0 < K; k0 += 32) {
    __syncthreads();
    for (int p = 0; p < 2; ++p) {
      int chunk = p * 256 + t;
      int row = chunk >> 2, c8 = (chunk & 3) << 3;
      gl_lds16(A  + (size_t)(m0 + row) * K + k0 + c8, As + (size_t)(p * 256 + wave * 64) * 8);
      gl_lds16(Bt + (size_t)(n0 + row) * K + k0 + c8, Bs + (size_t)(p * 256 + wave * 64) * 8);
    }
    __syncthreads();
    bf16x8 af[4], bfr[4];
    for (int i = 0; i < 4; ++i) af[i]  = *(const bf16x8*)(As + (wr + i * 16 + l15) * 32 + lq * 8);
    for (int j = 0; j < 4; ++j) bfr[j] = *(const bf16x8*)(Bs + (wc + j * 16 + l15) * 32 + lq * 8);
    for (int i = 0; i < 4; ++i)
      for (int j = 0; j < 4; ++j)
        acc[i][j] = mfma16(af[i], bfr[j], acc[i][j]);
  }

  for (int j = 0; j < 4; ++j) {
    int n = n0 + wc + j * 16 + l15;
    float bv = bias[n];
    for (int i = 0; i < 4; ++i) {
      int mbase = m0 + wr + i * 16 + lq * 4;
      for (int r = 0; r < 4; ++r) {
        size_t off = (size_t)(mbase + r) * N + n;
        float val = acc[i][j][r] + bv;
        if (obf) ((__bf16*)C)[off] = (__bf16)val;
        else     ((float*)C)[off]  = val;
      }
    }
  }
}

// ---------------- V pack: VTg[bh][kq][d][ik] = V[b][kq*4+ik][h][d] ----------------
// (key-quad-major so attn can stage it linearly with global_load_lds and read
//  4-key B-fragments for the K=16 PV MFMA with bank-spread ds_read_b64.)
__global__ __launch_bounds__(256) void vtrans_kernel(
    const __bf16* __restrict__ QKV, __bf16* __restrict__ VTg)
{
  __shared__ __bf16 tile[64][72];
  const int t = threadIdx.x;
  const int bh = blockIdx.y;
  const int b = bh / H_, h = bh - b * H_;
  const int s0 = blockIdx.x * 64;
  const __bf16* Vb = QKV + (size_t)b * S_ * NQKV + 1536 + h * 64;
  for (int rr = 0; rr < 2; ++rr) {
    int srow = rr * 32 + (t >> 3);
    int dcol = (t & 7) * 8;
    *(bf16x8*)&tile[srow][dcol] = *(const bf16x8*)(Vb + (size_t)(s0 + srow) * NQKV + dcol);
  }
  __syncthreads();
  // each thread emits 16 contiguous output elements: [kql][d0..d0+3][ik0..3]
  const int kql = t >> 4;            // 0..15 local key-quad
  const int d0  = (t & 15) * 4;      // 0,4,..,60
  __bf16 outv[16];
#pragma unroll
  for (int dd = 0; dd < 4; ++dd)
#pragma unroll
    for (int ik = 0; ik < 4; ++ik)
      outv[dd * 4 + ik] = tile[kql * 4 + ik][d0 + dd];
  __bf16* dst = VTg + ((size_t)bh * 512 + (s0 >> 2) + kql) * 256 + d0 * 4;
  *(bf16x8*)(dst)     = *(bf16x8*)(outv);
  *(bf16x8*)(dst + 8) = *(bf16x8*)(outv + 8);
}

// ---------------- attention: S^T x32 MFMA -> in-lane P -> K=16 PV MFMA (no transpose) ----
// Block: one (b,h), 128 q rows (32/wave), 64-key tiles staged in LDS via global_load_lds.
// l(q) computed by MFMA against a ones-fragment (no shuffles anywhere in the K-loop).
__global__ __launch_bounds__(256) void attn_kernel(
    const __bf16* __restrict__ QKV,    // [M][2304] (b,s,{q,k,v},h,d)
    const __bf16* __restrict__ VTg,    // [48][512][64][4]
    const float* __restrict__ maskAdd, // [4][2048]: 0 or -1e9
    __bf16* __restrict__ Out)          // [M][768] (b,s,h,d)
{
  __shared__ __align__(16) __bf16 Ks0[64 * 32];  // [key][d 0..31]
  __shared__ __align__(16) __bf16 Ks1[64 * 32];  // [key][d 32..63]
  __shared__ __align__(16) __bf16 Vt[16 * 256];  // [key-quad][d][4 keys]
  __shared__ __align__(16) float msk[64];

  const int t = threadIdx.x;
  const int w = t >> 6, lane = t & 63;
  const int l15 = lane & 15, qd = lane >> 4;
  const int bh = blockIdx.y;
  const int b = bh / H_, h = bh - b * H_;
  const int q0 = blockIdx.x * 128;

  const __bf16* Qb = QKV + (size_t)b * S_ * NQKV + h * 64;
  const __bf16* Kb = Qb + 768;
  const __bf16* Vg = VTg + (size_t)bh * 512 * 256;
  const float* mb = maskAdd + b * S_;

  // Q fragments (x32 B-operand: n=q at l15, k=d at qd*8+j): 2 q-subtiles x 2 d-halves
  bf16x8 qf[2][2];
#pragma unroll
  for (int sub = 0; sub < 2; ++sub) {
    int qrow = q0 + w * 32 + sub * 16 + l15;
    qf[sub][0] = *(const bf16x8*)(Qb + (size_t)qrow * NQKV + qd * 8);
    qf[sub][1] = *(const bf16x8*)(Qb + (size_t)qrow * NQKV + 32 + qd * 8);
  }

  const f32x4 z4 = {0.f, 0.f, 0.f, 0.f};
  f32x4 o[2][4];
#pragma unroll
  for (int sub = 0; sub < 2; ++sub)
#pragma unroll
    for (int dt = 0; dt < 4; ++dt) o[sub][dt] = z4;
  f32x4 ol[2] = {z4, z4};   // l accumulator via ones-MFMA: reg r holds l(q=qd*4+r)

  const short one_bf = (short)0x3F80;   // bf16 1.0
  const shortx4 ones4 = {one_bf, one_bf, one_bf, one_bf};

  const int skey = t >> 2;            // 0..63
  const int sch  = (t & 3) * 8;       // 0,8,16,24
  const float SC = 0.18033688011112042f;  // 0.125 * log2(e)

  for (int k0 = 0; k0 < S_; k0 += 64) {
    __syncthreads();
    gl_lds16(Kb + (size_t)(k0 + skey) * NQKV + sch,      Ks0 + w * 512);
    gl_lds16(Kb + (size_t)(k0 + skey) * NQKV + 32 + sch, Ks1 + w * 512);
    {
      const __bf16* vsrc = Vg + ((size_t)(k0 >> 2)) * 256;
      gl_lds16(vsrc + t * 8,        Vt + w * 512);
      gl_lds16(vsrc + 2048 + t * 8, Vt + 2048 + w * 512);
    }
    if (t < 16) gl_lds16(mb + k0 + lane * 4, msk);
    __syncthreads();

    // K fragments (x32 A-operand: m=key at l15, k=d): 4 key-tiles x 2 d-halves
    bf16x8 kf[4][2];
#pragma unroll
    for (int kt = 0; kt < 4; ++kt) {
      kf[kt][0] = *(const bf16x8*)(Ks0 + (kt * 16 + l15) * 32 + qd * 8);
      kf[kt][1] = *(const bf16x8*)(Ks1 + (kt * 16 + l15) * 32 + qd * 8);
    }
    // V fragments (K=16 B-operand: n=d at l15, k=key quad qd): [kt][dt]
    shortx4 vf[4][4];
#pragma unroll
    for (int kt = 0; kt < 4; ++kt)
#pragma unroll
      for (int dt = 0; dt < 4; ++dt)
        vf[kt][dt] = *(const shortx4*)(Vt + (kt * 4 + qd) * 256 + (dt * 16 + l15) * 4);
    // mask adds (broadcast reads)
    f32x4 ma[4];
#pragma unroll
    for (int kt = 0; kt < 4; ++kt) ma[kt] = *(const f32x4*)(msk + kt * 16 + qd * 4);

#pragma unroll
    for (int sub = 0; sub < 2; ++sub) {
      // S^T = K * Q^T : lane holds q=l15, keys kt*16 + qd*4 + r
      f32x4 s[4];
#pragma unroll
      for (int kt = 0; kt < 4; ++kt) {
        s[kt] = mfma16(kf[kt][0], qf[sub][0], z4);
        s[kt] = mfma16(kf[kt][1], qf[sub][1], s[kt]);
      }
      // p = exp2(s*SC + madd); pack to bf16 (RTZ via v_perm) -> already A-layout for K=16 MFMA
      shortx4 pfr[4];
#pragma unroll
      for (int kt = 0; kt < 4; ++kt) {
        float p0 = __builtin_amdgcn_exp2f(__builtin_fmaf(s[kt][0], SC, ma[kt][0]));
        float p1 = __builtin_amdgcn_exp2f(__builtin_fmaf(s[kt][1], SC, ma[kt][1]));
        float p2 = __builtin_amdgcn_exp2f(__builtin_fmaf(s[kt][2], SC, ma[kt][2]));
        float p3 = __builtin_amdgcn_exp2f(__builtin_fmaf(s[kt][3], SC, ma[kt][3]));
        unsigned int lo16 = __builtin_amdgcn_perm(__builtin_bit_cast(unsigned int, p1),
                                                  __builtin_bit_cast(unsigned int, p0), 0x07060302u);
        unsigned int hi16 = __builtin_amdgcn_perm(__builtin_bit_cast(unsigned int, p3),
                                                  __builtin_bit_cast(unsigned int, p2), 0x07060302u);
        uintx2 u = {lo16, hi16};
        pfr[kt] = __builtin_bit_cast(shortx4, u);
      }
      // O += P V ; l += P * ones
#pragma unroll
      for (int dt = 0; dt < 4; ++dt)
#pragma unroll
        for (int kt = 0; kt < 4; ++kt)
          o[sub][dt] = mfma_pv(pfr[kt], vf[kt][dt], o[sub][dt]);
#pragma unroll
      for (int kt = 0; kt < 4; ++kt)
        ol[sub] = mfma_pv(pfr[kt], ones4, ol[sub]);
    }
  }

  // finalize: l is in-lane (ol[sub][r] = l(q=qd*4+r), all d-cols identical)
#pragma unroll
  for (int sub = 0; sub < 2; ++sub) {
#pragma unroll
    for (int dt = 0; dt < 4; ++dt)
#pragma unroll
      for (int r = 0; r < 4; ++r) {
        int qrow = q0 + w * 32 + sub * 16 + qd * 4 + r;
        Out[(size_t)(b * S_ + qrow) * E_ + h * 64 + dt * 16 + l15] =
            (__bf16)(o[sub][dt][r] / ol[sub][r]);
      }
  }
}

extern "C" void kernel_launch(void* const* d_in, const int* in_sizes, int n_in,
                              void* d_out, int out_size, void* d_ws, size_t ws_size,
                              hipStream_t stream) {
  const void* x  = d_in[0];
  const int* mask = (const int*)d_in[1];
  const void* Wq = d_in[2];
  const void* bq = d_in[3];
  const void* Wk = d_in[4];
  const void* bk = d_in[5];
  const void* Wv = d_in[6];
  const void* bv = d_in[7];
  const void* Wo = d_in[8];
  const void* bo = d_in[9];

  char* ws = (char*)d_ws;
  int*    flag  = (int*)(ws + 0);
  __bf16* Xb    = (__bf16*)(ws + 256);        // 12582912 B -> ends 12583168
  __bf16* VTg   = Xb;                         // aliases Xb (dead after gemm1)
  __bf16* WbT   = (__bf16*)(ws + 12583168);   // 3538944  -> 16122112
  __bf16* WoT   = (__bf16*)(ws + 16122112);   // 1179648  -> 17301760
  float*  biasP = (float*)(ws + 17301760);    // 9216     -> 17310976
  float*  biasO = (float*)(ws + 17310976);    // 3072     -> 17314048
  __bf16* QKV   = (__bf16*)(ws + 17314048);   // 37748736 -> 55062784
  __bf16* attnO = (__bf16*)(ws + 55062784);   // 12582912 -> 67645696
  float*  maskA = (float*)(ws + 67645696);    // 32768    -> 67678464

  detect_kernel<<<dim3(1), dim3(256), 0, stream>>>((const unsigned short*)x, flag);
  convx_kernel<<<dim3(24576), dim3(256), 0, stream>>>(x, flag, Xb);
  pack_kernel<<<dim3(9216), dim3(256), 0, stream>>>(Wq, bq, Wk, bk, Wv, bv, Wo, bo, mask, flag,
                                                    WbT, WoT, biasP, biasO, maskA);
  gemm_bt_bias<<<dim3(64, 18), dim3(256), 0, stream>>>(Xb, WbT, biasP, QKV, NQKV, KDIM, flag, 1);
  vtrans_kernel<<<dim3(32, 48), dim3(256), 0, stream>>>(QKV, VTg);
  attn_kernel<<<dim3(16, 48), dim3(256), 0, stream>>>(QKV, VTg, maskA, attnO);
  gemm_bt_bias<<<dim3(64, 6), dim3(256), 0, stream>>>(attnO, WoT, biasO, d_out, E_, KDIM, flag, 0);
}

// Round 8
// 242.501 us; speedup vs baseline: 1.6655x; 1.2065x over previous
//
#include <hip/hip_runtime.h>
#include <hip/hip_bf16.h>

#define B_ 4
#define S_ 2048
#define E_ 768
#define H_ 12
#define D_ 64
#define M_ (B_*S_)      // 8192
#define NQKV 2304
#define KDIM 768

typedef __bf16 bf16x8 __attribute__((ext_vector_type(8)));
typedef float f32x4 __attribute__((ext_vector_type(4)));
typedef short shortx4 __attribute__((ext_vector_type(4)));
typedef unsigned int uintx2 __attribute__((ext_vector_type(2)));
typedef unsigned int uintx4 __attribute__((ext_vector_type(4)));

typedef __attribute__((address_space(1))) void gvoid;
typedef __attribute__((address_space(3))) void lvoid;

__device__ __forceinline__ void gl_lds16(const void* g, void* l) {
  __builtin_amdgcn_global_load_lds((gvoid*)g, (lvoid*)l, 16, 0, 0);
}

__device__ __forceinline__ f32x4 mfma16(bf16x8 a, bf16x8 b, f32x4 c) {
  return __builtin_amdgcn_mfma_f32_16x16x32_bf16(a, b, c, 0, 0, 0);
}

// PV MFMA: 16x16 tile, K=16. A/B: 4 bf16/lane, k = quad*4 + elem.
__device__ __forceinline__ f32x4 mfma_pv(shortx4 a, shortx4 b, f32x4 c) {
#if __has_builtin(__builtin_amdgcn_mfma_f32_16x16x16bf16_1k)
  return __builtin_amdgcn_mfma_f32_16x16x16bf16_1k(a, b, c, 0, 0, 0);
#else
  uintx2 au = __builtin_bit_cast(uintx2, a);
  uintx2 bu = __builtin_bit_cast(uintx2, b);
  uintx4 aw = {au.x, au.y, 0u, 0u};
  uintx4 bw = {bu.x, bu.y, 0u, 0u};
  return mfma16(__builtin_bit_cast(bf16x8, aw), __builtin_bit_cast(bf16x8, bw), c);
#endif
}

// Load element idx from a buffer that is either bf16 (is_bf=1) or fp32 (is_bf=0).
__device__ __forceinline__ __bf16 ldmix(const void* p, size_t idx, int is_bf) {
  if (is_bf) return ((const __bf16*)p)[idx];
  return (__bf16)(((const float*)p)[idx]);
}
__device__ __forceinline__ float ldmixf(const void* p, size_t idx, int is_bf) {
  if (is_bf) return (float)((const __bf16*)p)[idx];
  return ((const float*)p)[idx];
}

// ---------------- dtype detector (even u16 of fp32 = random mantissa bits) ----------------
__global__ void detect_kernel(const unsigned short* __restrict__ xr, int* __restrict__ flag) {
  __shared__ int cnt;
  if (threadIdx.x == 0) cnt = 0;
  __syncthreads();
  unsigned short h = xr[2 * threadIdx.x];
  int e = (h >> 7) & 0xFF;
  if (e >= 100 && e <= 140) atomicAdd(&cnt, 1);
  __syncthreads();
  if (threadIdx.x == 0) *flag = (cnt > 148) ? 1 : 0;   // 1 = inputs are bf16
}

// ---------------- x -> bf16 ----------------
__global__ __launch_bounds__(256) void convx_kernel(const void* __restrict__ x,
                                                    const int* __restrict__ flag,
                                                    __bf16* __restrict__ Xb) {
  const int is_bf = *flag;
  int idx = blockIdx.x * 256 + threadIdx.x;   // < 6291456
  Xb[idx] = ldmix(x, idx, is_bf);
}

// ---------------- mask compaction: per batch, list of kept key rows ----------------
// R[b][j] = global x-row (b*S + s) of the j-th kept key for j < n(kept);
// ALL remaining slots j in [n, S) are padded with a safe row (b*S) and
// maskC = -1e9 so tile-overhang gathers in gemm_kv stay in-bounds and
// pad keys contribute exactly zero in attn. (Round-7 crash: R was only
// padded to npad; gemm_kv's 128-row tiles gathered poison indices.)
__global__ __launch_bounds__(256) void scan_kernel(
    const int* __restrict__ mask,   // [B][S]
    int* __restrict__ R,            // [B][S]
    float* __restrict__ maskC,      // [B][S]
    int* __restrict__ npadArr)      // [B]
{
  __shared__ int wtot[4];
  __shared__ int runningS;
  const int t = threadIdx.x;
  const int w = t >> 6, lane = t & 63;
  const int b = blockIdx.x;
  if (t == 0) runningS = 0;
  __syncthreads();
  for (int k0 = 0; k0 < S_; k0 += 256) {
    int keep = (mask[b * S_ + k0 + t] != 0) ? 1 : 0;
    unsigned long long bal = __ballot(keep);
    int lanePre = __popcll(bal & ((1ull << lane) - 1ull));
    if (lane == 0) wtot[w] = __popcll(bal);
    __syncthreads();
    int base = runningS;
    for (int i = 0; i < w; ++i) base += wtot[i];
    if (keep) {
      int pos = base + lanePre;
      R[b * S_ + pos] = b * S_ + k0 + t;
      maskC[b * S_ + pos] = 0.f;
    }
    __syncthreads();
    if (t == 0) runningS += wtot[0] + wtot[1] + wtot[2] + wtot[3];
    __syncthreads();
  }
  int n = runningS;
  int np = (n + 63) & ~63;
  for (int j = n + t; j < S_; j += 256) {   // pad the FULL tail, not just to np
    R[b * S_ + j] = b * S_;                 // valid row; contribution killed by maskC
    maskC[b * S_ + j] = -1.0e9f;
  }
  if (t == 0) npadArr[b] = np;
}

// ---------------- weight pack ----------------
__global__ __launch_bounds__(256) void pack_kernel(
    const void* __restrict__ Wq, const void* __restrict__ bq,
    const void* __restrict__ Wk, const void* __restrict__ bk,
    const void* __restrict__ Wv, const void* __restrict__ bv,
    const void* __restrict__ Wo, const void* __restrict__ bo,
    const int* __restrict__ flag,
    __bf16* __restrict__ WbT, __bf16* __restrict__ WoT,
    float* __restrict__ biasP, float* __restrict__ biasO)
{
  const int is_bf = *flag;
  int idx = blockIdx.x * 256 + threadIdx.x;
  const int NW = NQKV * KDIM;   // 1769472
  if (idx < NW) {
    int n = idx / KDIM;
    int e = idx - n * KDIM;
    int sel = n / 768;
    int hd  = n - sel * 768;
    int h = hd >> 6, d = hd & 63;
    const void* W = (sel == 0) ? Wq : (sel == 1) ? Wk : Wv;
    WbT[idx] = ldmix(W, (size_t)(h * 768 + e) * 64 + d, is_bf);
  } else {
    int idx2 = idx - NW;        // < 589824
    int n = idx2 / 768;
    int k = idx2 - n * 768;
    WoT[idx2] = ldmix(Wo, (size_t)k * 768 + n, is_bf);
  }
  if (idx < NQKV) {
    int sel = idx / 768;
    int hd = idx - sel * 768;
    const void* bsel = (sel == 0) ? bq : (sel == 1) ? bk : bv;
    biasP[idx] = ldmixf(bsel, hd, is_bf);
  }
  if (idx >= NW && idx < NW + 768) {
    biasO[idx - NW] = ldmixf(bo, idx - NW, is_bf);
  }
}

// ---------------- GEMM: C[M][N] = A[M][K] * Bt[N][K]^T + bias[N]  (m97 structure) ----------------
__global__ __launch_bounds__(256) void gemm_bt_bias(
    const __bf16* __restrict__ A,
    const __bf16* __restrict__ Bt,
    const float* __restrict__ bias,
    void* __restrict__ C,
    int N, int K,
    const int* __restrict__ flag, int force_bf16)
{
  __shared__ __align__(16) __bf16 As[128 * 32];
  __shared__ __align__(16) __bf16 Bs[128 * 32];
  const int obf = force_bf16 | *flag;
  const int t = threadIdx.x;
  const int wave = t >> 6, lane = t & 63;
  const int l15 = lane & 15, lq = lane >> 4;
  const int m0 = blockIdx.x * 128;
  const int n0 = blockIdx.y * 128;
  const int wr = (wave >> 1) * 64;
  const int wc = (wave & 1) * 64;

  const f32x4 z4 = {0.f, 0.f, 0.f, 0.f};
  f32x4 acc[4][4];
  for (int i = 0; i < 4; ++i)
    for (int j = 0; j < 4; ++j) acc[i][j] = z4;

  for (int k0 = 0; k0 < K; k0 += 32) {
    __syncthreads();
    for (int p = 0; p < 2; ++p) {
      int chunk = p * 256 + t;
      int row = chunk >> 2, c8 = (chunk & 3) << 3;
      gl_lds16(A  + (size_t)(m0 + row) * K + k0 + c8, As + (size_t)(p * 256 + wave * 64) * 8);
      gl_lds16(Bt + (size_t)(n0 + row) * K + k0 + c8, Bs + (size_t)(p * 256 + wave * 64) * 8);
    }
    __syncthreads();
    bf16x8 af[4], bfr[4];
    for (int i = 0; i < 4; ++i) af[i]  = *(const bf16x8*)(As + (wr + i * 16 + l15) * 32 + lq * 8);
    for (int j = 0; j < 4; ++j) bfr[j] = *(const bf16x8*)(Bs + (wc + j * 16 + l15) * 32 + lq * 8);
    for (int i = 0; i < 4; ++i)
      for (int j = 0; j < 4; ++j)
        acc[i][j] = mfma16(af[i], bfr[j], acc[i][j]);
  }

  for (int j = 0; j < 4; ++j) {
    int n = n0 + wc + j * 16 + l15;
    float bv = bias[n];
    for (int i = 0; i < 4; ++i) {
      int mbase = m0 + wr + i * 16 + lq * 4;
      for (int r = 0; r < 4; ++r) {
        size_t off = (size_t)(mbase + r) * N + n;
        float val = acc[i][j][r] + bv;
        if (obf) ((__bf16*)C)[off] = (__bf16)val;
        else     ((float*)C)[off]  = val;
      }
    }
  }
}

// ---------------- K/V projection over COMPACTED rows (A gathered via R) ----------------
// Kc[bh][j][d], Vc[bh][j>>2][d][j&3]; bias from biasP[768+n].
__global__ __launch_bounds__(256) void gemm_kv(
    const __bf16* __restrict__ Xb,    // [8192][768]
    const __bf16* __restrict__ WbT,   // [2304][768] (rows 768.. are K then V)
    const float* __restrict__ biasP,
    const int* __restrict__ R,        // [B][2048] (fully padded with safe rows)
    const int* __restrict__ npadArr,  // [B]
    __bf16* __restrict__ Kc,          // [48][2048][64]
    __bf16* __restrict__ Vc)          // [48][512][256]
{
  __shared__ __align__(16) __bf16 As[128 * 32];
  __shared__ __align__(16) __bf16 Bs[128 * 32];
  const int t = threadIdx.x;
  const int wave = t >> 6, lane = t & 63;
  const int l15 = lane & 15, lq = lane >> 4;
  const int b = blockIdx.z;
  const int j0 = blockIdx.x * 128;
  if (j0 >= npadArr[b]) return;
  const int n0 = blockIdx.y * 128;        // within [0,1536)
  const int wr = (wave >> 1) * 64;
  const int wc = (wave & 1) * 64;
  const int c8 = (t & 3) << 3;

  // gathered A rows for the two staging passes (fixed across K-loop)
  const int rowA0 = R[b * S_ + j0 + ((0 * 256 + t) >> 2)];
  const int rowA1 = R[b * S_ + j0 + ((1 * 256 + t) >> 2)];

  const f32x4 z4 = {0.f, 0.f, 0.f, 0.f};
  f32x4 acc[4][4];
  for (int i = 0; i < 4; ++i)
    for (int j = 0; j < 4; ++j) acc[i][j] = z4;

  for (int k0 = 0; k0 < KDIM; k0 += 32) {
    __syncthreads();
    gl_lds16(Xb + (size_t)rowA0 * KDIM + k0 + c8, As + (size_t)(0 * 256 + wave * 64) * 8);
    gl_lds16(Xb + (size_t)rowA1 * KDIM + k0 + c8, As + (size_t)(1 * 256 + wave * 64) * 8);
    for (int p = 0; p < 2; ++p) {
      int chunk = p * 256 + t;
      int row = chunk >> 2;
      gl_lds16(WbT + (size_t)(768 + n0 + row) * KDIM + k0 + c8, Bs + (size_t)(p * 256 + wave * 64) * 8);
    }
    __syncthreads();
    bf16x8 af[4], bfr[4];
    for (int i = 0; i < 4; ++i) af[i]  = *(const bf16x8*)(As + (wr + i * 16 + l15) * 32 + lq * 8);
    for (int j = 0; j < 4; ++j) bfr[j] = *(const bf16x8*)(Bs + (wc + j * 16 + l15) * 32 + lq * 8);
    for (int i = 0; i < 4; ++i)
      for (int j = 0; j < 4; ++j)
        acc[i][j] = mfma16(af[i], bfr[j], acc[i][j]);
  }

  for (int j = 0; j < 4; ++j) {
    int n = n0 + wc + j * 16 + l15;            // 0..1535
    float bv = biasP[768 + n];
    const int isK = (n < 768);
    const int hh = (isK ? n : n - 768) >> 6;
    const int d  = n & 63;
    const size_t bhh = (size_t)(b * H_ + hh);
    for (int i = 0; i < 4; ++i) {
      int jbase = j0 + wr + i * 16 + lq * 4;
      for (int r = 0; r < 4; ++r) {
        int jj = jbase + r;
        __bf16 ov = (__bf16)(acc[i][j][r] + bv);
        if (isK) Kc[(bhh * 2048 + jj) * 64 + d] = ov;
        else     Vc[(bhh * 512 + (jj >> 2)) * 256 + d * 4 + (jj & 3)] = ov;
      }
    }
  }
}

// ---------------- attention over compacted keys ----------------
// Block: one (b,h), 128 q rows (32/wave), 64-key tiles, loop bound npad[b].
__global__ __launch_bounds__(256) void attn_kernel(
    const __bf16* __restrict__ Qc,     // [8192][768] (b,s,h,d)
    const __bf16* __restrict__ Kc,     // [48][2048][64]
    const __bf16* __restrict__ Vc,     // [48][512][256] quad layout
    const float* __restrict__ maskC,   // [4][2048]: 0 or -1e9 (pad)
    const int* __restrict__ npadArr,   // [4]
    __bf16* __restrict__ Out)          // [8192][768] (b,s,h,d)
{
  __shared__ __align__(16) __bf16 Ks0[64 * 32];  // [key][d 0..31]
  __shared__ __align__(16) __bf16 Ks1[64 * 32];  // [key][d 32..63]
  __shared__ __align__(16) __bf16 Vt[16 * 256];  // [key-quad][d][4 keys]
  __shared__ __align__(16) float msk[64];

  const int t = threadIdx.x;
  const int w = t >> 6, lane = t & 63;
  const int l15 = lane & 15, qd = lane >> 4;
  const int bh = blockIdx.y;
  const int b = bh / H_, h = bh - b * H_;
  const int q0 = blockIdx.x * 128;
  const int Skv = npadArr[b];

  const __bf16* Qb = Qc + (size_t)b * S_ * E_ + h * 64;
  const __bf16* Kb = Kc + (size_t)bh * 2048 * 64;
  const __bf16* Vg = Vc + (size_t)bh * 512 * 256;
  const float* mb = maskC + b * S_;

  // Q fragments (x32 B-operand: n=q at l15, k=d at qd*8+j): 2 q-subtiles x 2 d-halves
  bf16x8 qf[2][2];
#pragma unroll
  for (int sub = 0; sub < 2; ++sub) {
    int qrow = q0 + w * 32 + sub * 16 + l15;
    qf[sub][0] = *(const bf16x8*)(Qb + (size_t)qrow * E_ + qd * 8);
    qf[sub][1] = *(const bf16x8*)(Qb + (size_t)qrow * E_ + 32 + qd * 8);
  }

  const f32x4 z4 = {0.f, 0.f, 0.f, 0.f};
  f32x4 o[2][4];
#pragma unroll
  for (int sub = 0; sub < 2; ++sub)
#pragma unroll
    for (int dt = 0; dt < 4; ++dt) o[sub][dt] = z4;
  f32x4 ol[2] = {z4, z4};   // l accumulator via ones-MFMA

  const short one_bf = (short)0x3F80;   // bf16 1.0
  const shortx4 ones4 = {one_bf, one_bf, one_bf, one_bf};

  const int skey = t >> 2;            // 0..63
  const int sch  = (t & 3) * 8;       // 0,8,16,24
  const float SC = 0.18033688011112042f;  // 0.125 * log2(e)

  for (int k0 = 0; k0 < Skv; k0 += 64) {
    __syncthreads();
    gl_lds16(Kb + (size_t)(k0 + skey) * 64 + sch,      Ks0 + w * 512);
    gl_lds16(Kb + (size_t)(k0 + skey) * 64 + 32 + sch, Ks1 + w * 512);
    {
      const __bf16* vsrc = Vg + ((size_t)(k0 >> 2)) * 256;
      gl_lds16(vsrc + t * 8,        Vt + w * 512);
      gl_lds16(vsrc + 2048 + t * 8, Vt + 2048 + w * 512);
    }
    if (t < 16) gl_lds16(mb + k0 + lane * 4, msk);
    __syncthreads();

    // K fragments (x32 A-operand: m=key at l15, k=d): 4 key-tiles x 2 d-halves
    bf16x8 kf[4][2];
#pragma unroll
    for (int kt = 0; kt < 4; ++kt) {
      kf[kt][0] = *(const bf16x8*)(Ks0 + (kt * 16 + l15) * 32 + qd * 8);
      kf[kt][1] = *(const bf16x8*)(Ks1 + (kt * 16 + l15) * 32 + qd * 8);
    }
    // V fragments (K=16 B-operand: n=d at l15, k=key quad qd): [kt][dt]
    shortx4 vf[4][4];
#pragma unroll
    for (int kt = 0; kt < 4; ++kt)
#pragma unroll
      for (int dt = 0; dt < 4; ++dt)
        vf[kt][dt] = *(const shortx4*)(Vt + (kt * 4 + qd) * 256 + (dt * 16 + l15) * 4);
    // mask adds (broadcast reads)
    f32x4 ma[4];
#pragma unroll
    for (int kt = 0; kt < 4; ++kt) ma[kt] = *(const f32x4*)(msk + kt * 16 + qd * 4);

#pragma unroll
    for (int sub = 0; sub < 2; ++sub) {
      // S^T = K * Q^T : lane holds q=l15, keys kt*16 + qd*4 + r
      f32x4 s[4];
#pragma unroll
      for (int kt = 0; kt < 4; ++kt) {
        s[kt] = mfma16(kf[kt][0], qf[sub][0], z4);
        s[kt] = mfma16(kf[kt][1], qf[sub][1], s[kt]);
      }
      // p = exp2(s*SC + madd); pack to bf16 (RTZ via v_perm) -> A-layout for K=16 MFMA
      shortx4 pfr[4];
#pragma unroll
      for (int kt = 0; kt < 4; ++kt) {
        float p0 = __builtin_amdgcn_exp2f(__builtin_fmaf(s[kt][0], SC, ma[kt][0]));
        float p1 = __builtin_amdgcn_exp2f(__builtin_fmaf(s[kt][1], SC, ma[kt][1]));
        float p2 = __builtin_amdgcn_exp2f(__builtin_fmaf(s[kt][2], SC, ma[kt][2]));
        float p3 = __builtin_amdgcn_exp2f(__builtin_fmaf(s[kt][3], SC, ma[kt][3]));
        unsigned int lo16 = __builtin_amdgcn_perm(__builtin_bit_cast(unsigned int, p1),
                                                  __builtin_bit_cast(unsigned int, p0), 0x07060302u);
        unsigned int hi16 = __builtin_amdgcn_perm(__builtin_bit_cast(unsigned int, p3),
                                                  __builtin_bit_cast(unsigned int, p2), 0x07060302u);
        uintx2 u = {lo16, hi16};
        pfr[kt] = __builtin_bit_cast(shortx4, u);
      }
      // O += P V ; l += P * ones
#pragma unroll
      for (int dt = 0; dt < 4; ++dt)
#pragma unroll
        for (int kt = 0; kt < 4; ++kt)
          o[sub][dt] = mfma_pv(pfr[kt], vf[kt][dt], o[sub][dt]);
#pragma unroll
      for (int kt = 0; kt < 4; ++kt)
        ol[sub] = mfma_pv(pfr[kt], ones4, ol[sub]);
    }
  }

  // finalize
#pragma unroll
  for (int sub = 0; sub < 2; ++sub) {
#pragma unroll
    for (int dt = 0; dt < 4; ++dt)
#pragma unroll
      for (int r = 0; r < 4; ++r) {
        int qrow = q0 + w * 32 + sub * 16 + qd * 4 + r;
        Out[(size_t)(b * S_ + qrow) * E_ + h * 64 + dt * 16 + l15] =
            (__bf16)(o[sub][dt][r] / ol[sub][r]);
      }
  }
}

extern "C" void kernel_launch(void* const* d_in, const int* in_sizes, int n_in,
                              void* d_out, int out_size, void* d_ws, size_t ws_size,
                              hipStream_t stream) {
  const void* x  = d_in[0];
  const int* mask = (const int*)d_in[1];
  const void* Wq = d_in[2];
  const void* bq = d_in[3];
  const void* Wk = d_in[4];
  const void* bk = d_in[5];
  const void* Wv = d_in[6];
  const void* bv = d_in[7];
  const void* Wo = d_in[8];
  const void* bo = d_in[9];

  char* ws = (char*)d_ws;
  int*    flag  = (int*)(ws + 0);             // 256 B
  __bf16* Xb    = (__bf16*)(ws + 256);        // 12582912 -> 12583168
  __bf16* WbT   = (__bf16*)(ws + 12583168);   // 3538944  -> 16122112
  __bf16* WoT   = (__bf16*)(ws + 16122112);   // 1179648  -> 17301760
  float*  biasP = (float*)(ws + 17301760);    // 9216     -> 17310976
  float*  biasO = (float*)(ws + 17310976);    // 3072     -> 17314048
  __bf16* Qc    = (__bf16*)(ws + 17314048);   // 12582912 -> 29896960
  __bf16* Kc    = (__bf16*)(ws + 29896960);   // 12582912 -> 42479872
  __bf16* Vc    = (__bf16*)(ws + 42479872);   // 12582912 -> 55062784
  __bf16* attnO = (__bf16*)(ws + 55062784);   // 12582912 -> 67645696
  int*    Ridx  = (int*)(ws + 67645696);      // 32768    -> 67678464
  float*  maskC = (float*)(ws + 67678464);    // 32768    -> 67711232
  int*    npad  = (int*)(ws + 67711232);      // 16       -> 67711248

  detect_kernel<<<dim3(1), dim3(256), 0, stream>>>((const unsigned short*)x, flag);
  convx_kernel<<<dim3(24576), dim3(256), 0, stream>>>(x, flag, Xb);
  scan_kernel<<<dim3(B_), dim3(256), 0, stream>>>(mask, Ridx, maskC, npad);
  pack_kernel<<<dim3(9216), dim3(256), 0, stream>>>(Wq, bq, Wk, bk, Wv, bv, Wo, bo, flag,
                                                    WbT, WoT, biasP, biasO);
  gemm_bt_bias<<<dim3(64, 6), dim3(256), 0, stream>>>(Xb, WbT, biasP, Qc, E_, KDIM, flag, 1);
  gemm_kv<<<dim3(16, 12, B_), dim3(256), 0, stream>>>(Xb, WbT, biasP, Ridx, npad, Kc, Vc);
  attn_kernel<<<dim3(16, 48), dim3(256), 0, stream>>>(Qc, Kc, Vc, maskC, npad, attnO);
  gemm_bt_bias<<<dim3(64, 6), dim3(256), 0, stream>>>(attnO, WoT, biasO, d_out, E_, KDIM, flag, 0);
}

// Round 9
// 221.750 us; speedup vs baseline: 1.8213x; 1.0936x over previous
//
#include <hip/hip_runtime.h>
#include <hip/hip_bf16.h>

#define B_ 4
#define S_ 2048
#define E_ 768
#define H_ 12
#define D_ 64
#define M_ (B_*S_)      // 8192
#define NQKV 2304
#define KDIM 768

typedef __bf16 bf16x8 __attribute__((ext_vector_type(8)));
typedef float f32x4 __attribute__((ext_vector_type(4)));
typedef short shortx4 __attribute__((ext_vector_type(4)));
typedef unsigned int uintx2 __attribute__((ext_vector_type(2)));
typedef unsigned int uintx4 __attribute__((ext_vector_type(4)));

typedef __attribute__((address_space(1))) void gvoid;
typedef __attribute__((address_space(3))) void lvoid;

__device__ __forceinline__ void gl_lds16(const void* g, void* l) {
  __builtin_amdgcn_global_load_lds((gvoid*)g, (lvoid*)l, 16, 0, 0);
}

__device__ __forceinline__ f32x4 mfma16(bf16x8 a, bf16x8 b, f32x4 c) {
  return __builtin_amdgcn_mfma_f32_16x16x32_bf16(a, b, c, 0, 0, 0);
}

// PV MFMA: 16x16 tile, K=16. A/B: 4 bf16/lane, k = quad*4 + elem.
__device__ __forceinline__ f32x4 mfma_pv(shortx4 a, shortx4 b, f32x4 c) {
#if __has_builtin(__builtin_amdgcn_mfma_f32_16x16x16bf16_1k)
  return __builtin_amdgcn_mfma_f32_16x16x16bf16_1k(a, b, c, 0, 0, 0);
#else
  uintx2 au = __builtin_bit_cast(uintx2, a);
  uintx2 bu = __builtin_bit_cast(uintx2, b);
  uintx4 aw = {au.x, au.y, 0u, 0u};
  uintx4 bw = {bu.x, bu.y, 0u, 0u};
  return mfma16(__builtin_bit_cast(bf16x8, aw), __builtin_bit_cast(bf16x8, bw), c);
#endif
}

// Load element idx from a buffer that is either bf16 (is_bf=1) or fp32 (is_bf=0).
__device__ __forceinline__ __bf16 ldmix(const void* p, size_t idx, int is_bf) {
  if (is_bf) return ((const __bf16*)p)[idx];
  return (__bf16)(((const float*)p)[idx]);
}
__device__ __forceinline__ float ldmixf(const void* p, size_t idx, int is_bf) {
  if (is_bf) return (float)((const __bf16*)p)[idx];
  return ((const float*)p)[idx];
}

// ---------------- detect (block 0) + mask scan (blocks 1..4) ----------------
__global__ __launch_bounds__(256) void detect_scan_kernel(
    const unsigned short* __restrict__ xr, int* __restrict__ flag,
    const int* __restrict__ mask,
    int* __restrict__ R, float* __restrict__ maskC, int* __restrict__ npadArr)
{
  __shared__ int cnt;
  __shared__ int wtot[4];
  __shared__ int runningS;
  const int t = threadIdx.x;
  if (blockIdx.x == 0) {
    // dtype detect: even u16 of fp32 = random mantissa bits (~16% in range);
    // bf16 N(0,1) data ~100% in range.
    if (t == 0) cnt = 0;
    __syncthreads();
    unsigned short h = xr[2 * t];
    int e = (h >> 7) & 0xFF;
    if (e >= 100 && e <= 140) atomicAdd(&cnt, 1);
    __syncthreads();
    if (t == 0) *flag = (cnt > 148) ? 1 : 0;   // 1 = inputs are bf16
    return;
  }
  const int w = t >> 6, lane = t & 63;
  const int b = blockIdx.x - 1;
  if (t == 0) runningS = 0;
  __syncthreads();
  for (int k0 = 0; k0 < S_; k0 += 256) {
    int keep = (mask[b * S_ + k0 + t] != 0) ? 1 : 0;
    unsigned long long bal = __ballot(keep);
    int lanePre = __popcll(bal & ((1ull << lane) - 1ull));
    if (lane == 0) wtot[w] = __popcll(bal);
    __syncthreads();
    int base = runningS;
    for (int i = 0; i < w; ++i) base += wtot[i];
    if (keep) {
      int pos = base + lanePre;
      R[b * S_ + pos] = b * S_ + k0 + t;
      maskC[b * S_ + pos] = 0.f;
    }
    __syncthreads();
    if (t == 0) runningS += wtot[0] + wtot[1] + wtot[2] + wtot[3];
    __syncthreads();
  }
  int n = runningS;
  int np = (n + 63) & ~63;
  for (int j = n + t; j < S_; j += 256) {   // pad the FULL tail (safe gather rows)
    R[b * S_ + j] = b * S_;
    maskC[b * S_ + j] = -1.0e9f;
  }
  if (t == 0) npadArr[b] = np;
}

// ---------------- prep: x->bf16 (vectorized x8) + weight pack ----------------
__global__ __launch_bounds__(256) void prep_kernel(
    const void* __restrict__ x,
    const void* __restrict__ Wq, const void* __restrict__ bq,
    const void* __restrict__ Wk, const void* __restrict__ bk,
    const void* __restrict__ Wv, const void* __restrict__ bv,
    const void* __restrict__ Wo, const void* __restrict__ bo,
    const int* __restrict__ flag,
    __bf16* __restrict__ Xb,
    __bf16* __restrict__ WbT, __bf16* __restrict__ WoT,
    float* __restrict__ biasP, float* __restrict__ biasO)
{
  const int is_bf = *flag;
  const int bid = blockIdx.x;
  const int t = threadIdx.x;
  if (bid < 3072) {                       // convx: 3072*256*8 = 6291456 elems
    int base = (bid * 256 + t) * 8;
    if (is_bf) {
      *(uintx4*)(Xb + base) = *(const uintx4*)((const __bf16*)x + base);
    } else {
      const float* xf = (const float*)x + base;
      f32x4 a = *(const f32x4*)xf;
      f32x4 c = *(const f32x4*)(xf + 4);
      __bf16 ov[8] = {(__bf16)a[0], (__bf16)a[1], (__bf16)a[2], (__bf16)a[3],
                      (__bf16)c[0], (__bf16)c[1], (__bf16)c[2], (__bf16)c[3]};
      *(uintx4*)(Xb + base) = *(uintx4*)ov;
    }
    return;
  }
  int idx = (bid - 3072) * 256 + t;       // pack: < 2359296
  const int NW = NQKV * KDIM;             // 1769472
  if (idx < NW) {
    int n = idx / KDIM;
    int e = idx - n * KDIM;
    int sel = n / 768;
    int hd  = n - sel * 768;
    int h = hd >> 6, d = hd & 63;
    const void* W = (sel == 0) ? Wq : (sel == 1) ? Wk : Wv;
    WbT[idx] = ldmix(W, (size_t)(h * 768 + e) * 64 + d, is_bf);
  } else {
    int idx2 = idx - NW;                  // < 589824
    int n = idx2 / 768;
    int k = idx2 - n * 768;
    WoT[idx2] = ldmix(Wo, (size_t)k * 768 + n, is_bf);
  }
  if (idx < NQKV) {
    int sel = idx / 768;
    int hd = idx - sel * 768;
    const void* bsel = (sel == 0) ? bq : (sel == 1) ? bk : bv;
    biasP[idx] = ldmixf(bsel, hd, is_bf);
  }
  if (idx >= NW && idx < NW + 768) {
    biasO[idx - NW] = ldmixf(bo, idx - NW, is_bf);
  }
}

// ---------------- fused Q + K/V projection, 128x64 tiles ----------------
// bid < 768: Q part (dense rows, N=768 -> Qc). bid >= 768: KV part (gathered
// compacted rows per batch, N=1536 -> Kc/Vc). 128x64 tile = 4 waves of 64x32;
// 2304 blocks total (~1632 active) => 3+ blocks/CU for latency hiding.
__global__ __launch_bounds__(256) void gemm_qkv(
    const __bf16* __restrict__ Xb,    // [8192][768]
    const __bf16* __restrict__ WbT,   // [2304][768]
    const float* __restrict__ biasP,  // [2304]
    const int* __restrict__ R,        // [B][2048] fully padded
    const int* __restrict__ npadArr,  // [B]
    __bf16* __restrict__ Qc,          // [8192][768]
    __bf16* __restrict__ Kc,          // [48][2048][64]
    __bf16* __restrict__ Vc)          // [48][512][256]
{
  __shared__ __align__(16) __bf16 As[128 * 32];
  __shared__ __align__(16) __bf16 Bs[64 * 32];
  const int t = threadIdx.x;
  const int wave = t >> 6, lane = t & 63;
  const int l15 = lane & 15, lq = lane >> 4;
  const int wm = (wave & 1) * 64;
  const int wn = (wave >> 1) * 32;

  const int bid = blockIdx.x;
  int m0, bn0, isQ, b = 0;
  int rowA0, rowA1;
  if (bid < 768) {
    isQ = 1;
    int mi = bid / 12, ni = bid - mi * 12;
    m0 = mi * 128; bn0 = ni * 64;
    rowA0 = m0 + ((0 * 256 + t) >> 2);
    rowA1 = m0 + ((1 * 256 + t) >> 2);
  } else {
    isQ = 0;
    int r2 = bid - 768;
    b = r2 / 384;
    int rr = r2 - b * 384;
    int mi = rr / 24, ni = rr - mi * 24;
    if (mi * 128 >= npadArr[b]) return;
    m0 = mi * 128;
    bn0 = 768 + ni * 64;
    rowA0 = R[b * S_ + m0 + ((0 * 256 + t) >> 2)];
    rowA1 = R[b * S_ + m0 + ((1 * 256 + t) >> 2)];
  }
  const int c8 = (t & 3) << 3;
  const int brow = t >> 2;                 // 0..63

  const f32x4 z4 = {0.f, 0.f, 0.f, 0.f};
  f32x4 acc[4][2];
#pragma unroll
  for (int i = 0; i < 4; ++i)
#pragma unroll
    for (int j = 0; j < 2; ++j) acc[i][j] = z4;

  for (int k0 = 0; k0 < KDIM; k0 += 32) {
    __syncthreads();
    gl_lds16(Xb + (size_t)rowA0 * KDIM + k0 + c8, As + (size_t)(wave * 64) * 8);
    gl_lds16(Xb + (size_t)rowA1 * KDIM + k0 + c8, As + (size_t)(256 + wave * 64) * 8);
    gl_lds16(WbT + (size_t)(bn0 + brow) * KDIM + k0 + c8, Bs + (size_t)(wave * 64) * 8);
    __syncthreads();
    bf16x8 af[4], bfr[2];
#pragma unroll
    for (int i = 0; i < 4; ++i) af[i]  = *(const bf16x8*)(As + (wm + i * 16 + l15) * 32 + lq * 8);
#pragma unroll
    for (int j = 0; j < 2; ++j) bfr[j] = *(const bf16x8*)(Bs + (wn + j * 16 + l15) * 32 + lq * 8);
#pragma unroll
    for (int i = 0; i < 4; ++i)
#pragma unroll
      for (int j = 0; j < 2; ++j)
        acc[i][j] = mfma16(af[i], bfr[j], acc[i][j]);
  }

#pragma unroll
  for (int j = 0; j < 2; ++j) {
    int nn = (bn0 - (isQ ? 0 : 768)) + wn + j * 16 + l15;   // col within 768/1536
    float bv = biasP[(isQ ? 0 : 768) + nn];
    if (isQ) {
#pragma unroll
      for (int i = 0; i < 4; ++i) {
        int mbase = m0 + wm + i * 16 + lq * 4;
#pragma unroll
        for (int r = 0; r < 4; ++r)
          Qc[(size_t)(mbase + r) * 768 + nn] = (__bf16)(acc[i][j][r] + bv);
      }
    } else {
      const int isK = (nn < 768);
      const int hh = (isK ? nn : nn - 768) >> 6;
      const int d  = nn & 63;
      const size_t bhh = (size_t)(b * H_ + hh);
#pragma unroll
      for (int i = 0; i < 4; ++i) {
        int jbase = m0 + wm + i * 16 + lq * 4;
#pragma unroll
        for (int r = 0; r < 4; ++r) {
          int jj = jbase + r;
          __bf16 ov = (__bf16)(acc[i][j][r] + bv);
          if (isK) Kc[(bhh * 2048 + jj) * 64 + d] = ov;
          else     Vc[(bhh * 512 + (jj >> 2)) * 256 + d * 4 + (jj & 3)] = ov;
        }
      }
    }
  }
}

// ---------------- output projection, 128x64 tiles (768 blocks) ----------------
__global__ __launch_bounds__(256) void gemm_out(
    const __bf16* __restrict__ A,     // [8192][768] attn out
    const __bf16* __restrict__ WoT,   // [768][768]
    const float* __restrict__ biasO,  // [768]
    void* __restrict__ C,             // [8192][768] fp32 or bf16 per flag
    const int* __restrict__ flag)
{
  __shared__ __align__(16) __bf16 As[128 * 32];
  __shared__ __align__(16) __bf16 Bs[64 * 32];
  const int obf = *flag;
  const int t = threadIdx.x;
  const int wave = t >> 6, lane = t & 63;
  const int l15 = lane & 15, lq = lane >> 4;
  const int wm = (wave & 1) * 64;
  const int wn = (wave >> 1) * 32;
  const int m0 = blockIdx.x * 128;
  const int n0 = blockIdx.y * 64;
  const int c8 = (t & 3) << 3;
  const int brow = t >> 2;
  const int rowA0 = m0 + ((0 * 256 + t) >> 2);
  const int rowA1 = m0 + ((1 * 256 + t) >> 2);

  const f32x4 z4 = {0.f, 0.f, 0.f, 0.f};
  f32x4 acc[4][2];
#pragma unroll
  for (int i = 0; i < 4; ++i)
#pragma unroll
    for (int j = 0; j < 2; ++j) acc[i][j] = z4;

  for (int k0 = 0; k0 < KDIM; k0 += 32) {
    __syncthreads();
    gl_lds16(A + (size_t)rowA0 * KDIM + k0 + c8, As + (size_t)(wave * 64) * 8);
    gl_lds16(A + (size_t)rowA1 * KDIM + k0 + c8, As + (size_t)(256 + wave * 64) * 8);
    gl_lds16(WoT + (size_t)(n0 + brow) * KDIM + k0 + c8, Bs + (size_t)(wave * 64) * 8);
    __syncthreads();
    bf16x8 af[4], bfr[2];
#pragma unroll
    for (int i = 0; i < 4; ++i) af[i]  = *(const bf16x8*)(As + (wm + i * 16 + l15) * 32 + lq * 8);
#pragma unroll
    for (int j = 0; j < 2; ++j) bfr[j] = *(const bf16x8*)(Bs + (wn + j * 16 + l15) * 32 + lq * 8);
#pragma unroll
    for (int i = 0; i < 4; ++i)
#pragma unroll
      for (int j = 0; j < 2; ++j)
        acc[i][j] = mfma16(af[i], bfr[j], acc[i][j]);
  }

#pragma unroll
  for (int j = 0; j < 2; ++j) {
    int n = n0 + wn + j * 16 + l15;
    float bv = biasO[n];
#pragma unroll
    for (int i = 0; i < 4; ++i) {
      int mbase = m0 + wm + i * 16 + lq * 4;
#pragma unroll
      for (int r = 0; r < 4; ++r) {
        size_t off = (size_t)(mbase + r) * 768 + n;
        float val = acc[i][j][r] + bv;
        if (obf) ((__bf16*)C)[off] = (__bf16)val;
        else     ((float*)C)[off]  = val;
      }
    }
  }
}

// ---------------- attention over compacted keys (unchanged from round 8) ----------------
__global__ __launch_bounds__(256) void attn_kernel(
    const __bf16* __restrict__ Qc,     // [8192][768] (b,s,h,d)
    const __bf16* __restrict__ Kc,     // [48][2048][64]
    const __bf16* __restrict__ Vc,     // [48][512][256] quad layout
    const float* __restrict__ maskC,   // [4][2048]: 0 or -1e9 (pad)
    const int* __restrict__ npadArr,   // [4]
    __bf16* __restrict__ Out)          // [8192][768] (b,s,h,d)
{
  __shared__ __align__(16) __bf16 Ks0[64 * 32];  // [key][d 0..31]
  __shared__ __align__(16) __bf16 Ks1[64 * 32];  // [key][d 32..63]
  __shared__ __align__(16) __bf16 Vt[16 * 256];  // [key-quad][d][4 keys]
  __shared__ __align__(16) float msk[64];

  const int t = threadIdx.x;
  const int w = t >> 6, lane = t & 63;
  const int l15 = lane & 15, qd = lane >> 4;
  const int bh = blockIdx.y;
  const int b = bh / H_, h = bh - b * H_;
  const int q0 = blockIdx.x * 128;
  const int Skv = npadArr[b];

  const __bf16* Qb = Qc + (size_t)b * S_ * E_ + h * 64;
  const __bf16* Kb = Kc + (size_t)bh * 2048 * 64;
  const __bf16* Vg = Vc + (size_t)bh * 512 * 256;
  const float* mb = maskC + b * S_;

  bf16x8 qf[2][2];
#pragma unroll
  for (int sub = 0; sub < 2; ++sub) {
    int qrow = q0 + w * 32 + sub * 16 + l15;
    qf[sub][0] = *(const bf16x8*)(Qb + (size_t)qrow * E_ + qd * 8);
    qf[sub][1] = *(const bf16x8*)(Qb + (size_t)qrow * E_ + 32 + qd * 8);
  }

  const f32x4 z4 = {0.f, 0.f, 0.f, 0.f};
  f32x4 o[2][4];
#pragma unroll
  for (int sub = 0; sub < 2; ++sub)
#pragma unroll
    for (int dt = 0; dt < 4; ++dt) o[sub][dt] = z4;
  f32x4 ol[2] = {z4, z4};

  const short one_bf = (short)0x3F80;
  const shortx4 ones4 = {one_bf, one_bf, one_bf, one_bf};

  const int skey = t >> 2;
  const int sch  = (t & 3) * 8;
  const float SC = 0.18033688011112042f;  // 0.125 * log2(e)

  for (int k0 = 0; k0 < Skv; k0 += 64) {
    __syncthreads();
    gl_lds16(Kb + (size_t)(k0 + skey) * 64 + sch,      Ks0 + w * 512);
    gl_lds16(Kb + (size_t)(k0 + skey) * 64 + 32 + sch, Ks1 + w * 512);
    {
      const __bf16* vsrc = Vg + ((size_t)(k0 >> 2)) * 256;
      gl_lds16(vsrc + t * 8,        Vt + w * 512);
      gl_lds16(vsrc + 2048 + t * 8, Vt + 2048 + w * 512);
    }
    if (t < 16) gl_lds16(mb + k0 + lane * 4, msk);
    __syncthreads();

    bf16x8 kf[4][2];
#pragma unroll
    for (int kt = 0; kt < 4; ++kt) {
      kf[kt][0] = *(const bf16x8*)(Ks0 + (kt * 16 + l15) * 32 + qd * 8);
      kf[kt][1] = *(const bf16x8*)(Ks1 + (kt * 16 + l15) * 32 + qd * 8);
    }
    shortx4 vf[4][4];
#pragma unroll
    for (int kt = 0; kt < 4; ++kt)
#pragma unroll
      for (int dt = 0; dt < 4; ++dt)
        vf[kt][dt] = *(const shortx4*)(Vt + (kt * 4 + qd) * 256 + (dt * 16 + l15) * 4);
    f32x4 ma[4];
#pragma unroll
    for (int kt = 0; kt < 4; ++kt) ma[kt] = *(const f32x4*)(msk + kt * 16 + qd * 4);

#pragma unroll
    for (int sub = 0; sub < 2; ++sub) {
      f32x4 s[4];
#pragma unroll
      for (int kt = 0; kt < 4; ++kt) {
        s[kt] = mfma16(kf[kt][0], qf[sub][0], z4);
        s[kt] = mfma16(kf[kt][1], qf[sub][1], s[kt]);
      }
      shortx4 pfr[4];
#pragma unroll
      for (int kt = 0; kt < 4; ++kt) {
        float p0 = __builtin_amdgcn_exp2f(__builtin_fmaf(s[kt][0], SC, ma[kt][0]));
        float p1 = __builtin_amdgcn_exp2f(__builtin_fmaf(s[kt][1], SC, ma[kt][1]));
        float p2 = __builtin_amdgcn_exp2f(__builtin_fmaf(s[kt][2], SC, ma[kt][2]));
        float p3 = __builtin_amdgcn_exp2f(__builtin_fmaf(s[kt][3], SC, ma[kt][3]));
        unsigned int lo16 = __builtin_amdgcn_perm(__builtin_bit_cast(unsigned int, p1),
                                                  __builtin_bit_cast(unsigned int, p0), 0x07060302u);
        unsigned int hi16 = __builtin_amdgcn_perm(__builtin_bit_cast(unsigned int, p3),
                                                  __builtin_bit_cast(unsigned int, p2), 0x07060302u);
        uintx2 u = {lo16, hi16};
        pfr[kt] = __builtin_bit_cast(shortx4, u);
      }
#pragma unroll
      for (int dt = 0; dt < 4; ++dt)
#pragma unroll
        for (int kt = 0; kt < 4; ++kt)
          o[sub][dt] = mfma_pv(pfr[kt], vf[kt][dt], o[sub][dt]);
#pragma unroll
      for (int kt = 0; kt < 4; ++kt)
        ol[sub] = mfma_pv(pfr[kt], ones4, ol[sub]);
    }
  }

#pragma unroll
  for (int sub = 0; sub < 2; ++sub) {
#pragma unroll
    for (int dt = 0; dt < 4; ++dt)
#pragma unroll
      for (int r = 0; r < 4; ++r) {
        int qrow = q0 + w * 32 + sub * 16 + qd * 4 + r;
        Out[(size_t)(b * S_ + qrow) * E_ + h * 64 + dt * 16 + l15] =
            (__bf16)(o[sub][dt][r] / ol[sub][r]);
      }
  }
}

extern "C" void kernel_launch(void* const* d_in, const int* in_sizes, int n_in,
                              void* d_out, int out_size, void* d_ws, size_t ws_size,
                              hipStream_t stream) {
  const void* x  = d_in[0];
  const int* mask = (const int*)d_in[1];
  const void* Wq = d_in[2];
  const void* bq = d_in[3];
  const void* Wk = d_in[4];
  const void* bk = d_in[5];
  const void* Wv = d_in[6];
  const void* bv = d_in[7];
  const void* Wo = d_in[8];
  const void* bo = d_in[9];

  char* ws = (char*)d_ws;
  int*    flag  = (int*)(ws + 0);             // 256 B
  __bf16* Xb    = (__bf16*)(ws + 256);        // 12582912 -> 12583168
  __bf16* WbT   = (__bf16*)(ws + 12583168);   // 3538944  -> 16122112
  __bf16* WoT   = (__bf16*)(ws + 16122112);   // 1179648  -> 17301760
  float*  biasP = (float*)(ws + 17301760);    // 9216     -> 17310976
  float*  biasO = (float*)(ws + 17310976);    // 3072     -> 17314048
  __bf16* Qc    = (__bf16*)(ws + 17314048);   // 12582912 -> 29896960
  __bf16* Kc    = (__bf16*)(ws + 29896960);   // 12582912 -> 42479872
  __bf16* Vc    = (__bf16*)(ws + 42479872);   // 12582912 -> 55062784
  __bf16* attnO = (__bf16*)(ws + 55062784);   // 12582912 -> 67645696
  int*    Ridx  = (int*)(ws + 67645696);      // 32768    -> 67678464
  float*  maskC = (float*)(ws + 67678464);    // 32768    -> 67711232
  int*    npad  = (int*)(ws + 67711232);      // 16       -> 67711248

  detect_scan_kernel<<<dim3(5), dim3(256), 0, stream>>>(
      (const unsigned short*)x, flag, mask, Ridx, maskC, npad);
  prep_kernel<<<dim3(12288), dim3(256), 0, stream>>>(
      x, Wq, bq, Wk, bk, Wv, bv, Wo, bo, flag, Xb, WbT, WoT, biasP, biasO);
  gemm_qkv<<<dim3(2304), dim3(256), 0, stream>>>(Xb, WbT, biasP, Ridx, npad, Qc, Kc, Vc);
  attn_kernel<<<dim3(16, 48), dim3(256), 0, stream>>>(Qc, Kc, Vc, maskC, npad, attnO);
  gemm_out<<<dim3(64, 12), dim3(256), 0, stream>>>(attnO, WoT, biasO, d_out, flag);
}